// Round 2
// baseline (7463.533 us; speedup 1.0000x reference)
//
#include <hip/hip_runtime.h>
#include <math.h>

#define BATCH 16
#define NPTS  2048
#define DIM   768

// ---------------- normalize: fn = f / max(||f||,1e-12), fp64 norm ----------------
__global__ void normalize_k(const float* __restrict__ feat, float* __restrict__ fn, int cs) {
  const int rn = blockIdx.x;                 // ci*NPTS + n
  const int ci = rn >> 11, n = rn & (NPTS - 1);
  const float* src = feat + ((size_t)(cs + ci) * NPTS + n) * DIM;
  const int t = threadIdx.x;                 // 256 threads
  float f0 = src[t], f1 = src[t + 256], f2 = src[t + 512];
  double s = (double)f0 * (double)f0 + (double)f1 * (double)f1 + (double)f2 * (double)f2;
  for (int off = 32; off > 0; off >>= 1) s += __shfl_down(s, off);
  __shared__ double ps[4];
  __shared__ double rbc;
  const int lane = t & 63, wid = t >> 6;
  if (lane == 0) ps[wid] = s;
  __syncthreads();
  if (t == 0) {
    double tot = ps[0] + ps[1] + ps[2] + ps[3];
    rbc = fmax(sqrt(tot), 1e-12);
  }
  __syncthreads();
  const double r = rbc;
  float* dst = fn + ((size_t)ci * NPTS + n) * DIM;
  dst[t]       = (float)((double)f0 / r);
  dst[t + 256] = (float)((double)f1 / r);
  dst[t + 512] = (float)((double)f2 / r);
}

// ---------------- similarity: S = fn.fn^T (fp64 acc) + 0.5*exp(-d2/1e4) ----------------
// Symmetric: only tiles bx<=by computed; both (i,j) and (j,i) written.
// 128x128 tile per block (16x16 threads, 8x8 fp64 micro-tile), k-chunk 16.
__global__ __launch_bounds__(256, 2) void gemm_k(const float* __restrict__ fn,
                                                 const float* __restrict__ coords,
                                                 float* __restrict__ S, int cs) {
  if (blockIdx.x > blockIdx.y) return;       // lower-triangle tiles skipped (symmetry)
  const int ci = blockIdx.z;
  const int i0 = blockIdx.x * 128;
  const int j0 = blockIdx.y * 128;
  const int tx = threadIdx.x, ty = threadIdx.y;
  const int tid = ty * 16 + tx;
  __shared__ double Ad[16][130];   // [k][i], k-major: B-reads conflict-free, A-reads broadcast
  __shared__ double Bd[16][130];
  double acc[8][8];
#pragma unroll
  for (int r = 0; r < 8; ++r)
#pragma unroll
    for (int c = 0; c < 8; ++c) acc[r][c] = 0.0;

  const float* fb = fn + (size_t)ci * NPTS * DIM;
  const int row = tid >> 1;      // 0..127
  const int half = tid & 1;      // which 8-wide k slice

  for (int k0 = 0; k0 < DIM; k0 += 16) {
    __syncthreads();
    {
      const float* sa = fb + (size_t)(i0 + row) * DIM + k0 + half * 8;
      float4 a0 = *(const float4*)sa;
      float4 a1 = *(const float4*)(sa + 4);
      const int kk = half * 8;
      Ad[kk + 0][row] = a0.x; Ad[kk + 1][row] = a0.y; Ad[kk + 2][row] = a0.z; Ad[kk + 3][row] = a0.w;
      Ad[kk + 4][row] = a1.x; Ad[kk + 5][row] = a1.y; Ad[kk + 6][row] = a1.z; Ad[kk + 7][row] = a1.w;
      const float* sb = fb + (size_t)(j0 + row) * DIM + k0 + half * 8;
      float4 b0 = *(const float4*)sb;
      float4 b1 = *(const float4*)(sb + 4);
      Bd[kk + 0][row] = b0.x; Bd[kk + 1][row] = b0.y; Bd[kk + 2][row] = b0.z; Bd[kk + 3][row] = b0.w;
      Bd[kk + 4][row] = b1.x; Bd[kk + 5][row] = b1.y; Bd[kk + 6][row] = b1.z; Bd[kk + 7][row] = b1.w;
    }
    __syncthreads();
#pragma unroll
    for (int k = 0; k < 16; ++k) {
      double a[8], b[8];
      const double* ap = &Ad[k][8 * ty];
#pragma unroll
      for (int r = 0; r < 8; r += 2) { double2 v = *(const double2*)(ap + r); a[r] = v.x; a[r + 1] = v.y; }
#pragma unroll
      for (int c = 0; c < 8; ++c) b[c] = Bd[k][tx + 16 * c];
#pragma unroll
      for (int r = 0; r < 8; ++r)
#pragma unroll
        for (int c = 0; c < 8; ++c) acc[r][c] = fma(a[r], b[c], acc[r][c]);
    }
  }

  // epilogue: + 0.5 * exp(-sq_dist/10000), exp via 4th-order Taylor (x<=2e-4, err ~1e-20)
  const float* cb = coords + (size_t)(cs + ci) * NPTS * 2;
  double cxi[8], cyi[8], cxj[8], cyj[8];
#pragma unroll
  for (int r = 0; r < 8; ++r) { float2 p = *(const float2*)(cb + 2 * (i0 + 8 * ty + r)); cxi[r] = p.x; cyi[r] = p.y; }
#pragma unroll
  for (int c = 0; c < 8; ++c) { float2 p = *(const float2*)(cb + 2 * (j0 + tx + 16 * c)); cxj[c] = p.x; cyj[c] = p.y; }
  float* Sb = S + (size_t)ci * NPTS * NPTS;

#define FINV(r, c) ({                                                                   \
    double dx_ = cxi[r] - cxj[c], dy_ = cyi[r] - cyj[c];                                \
    double x_ = (dx_ * dx_ + dy_ * dy_) * (1.0 / 10000.0);                              \
    double e_ = 1.0 - x_ * (1.0 - x_ * (0.5 - x_ * ((1.0 / 6.0) - x_ * (1.0 / 24.0)))); \
    (float)(acc[r][c] + 0.5 * e_); })

  // straight write: S[i0.., j0..]
#pragma unroll
  for (int r = 0; r < 8; ++r) {
    float* orow = Sb + (size_t)(i0 + 8 * ty + r) * NPTS + j0;
#pragma unroll
    for (int c = 0; c < 8; ++c) orow[tx + 16 * c] = FINV(r, c);
  }
  // transposed write: S[j0.., i0..] (bitwise-identical values; diagonal tiles overwrite same data)
#pragma unroll
  for (int c = 0; c < 8; ++c) {
    float* trow = Sb + (size_t)(j0 + tx + 16 * c) * NPTS + i0 + 8 * ty;
    float4 q0 = make_float4(FINV(0, c), FINV(1, c), FINV(2, c), FINV(3, c));
    float4 q1 = make_float4(FINV(4, c), FINV(5, c), FINV(6, c), FINV(7, c));
    ((float4*)trow)[0] = q0;
    ((float4*)trow)[1] = q1;
  }
#undef FINV
}

// ---------------- row sums (fp64) for start-node selection ----------------
__global__ void rowsum_k(const float* __restrict__ S, double* __restrict__ rs) {
  const size_t r = blockIdx.x;
  const float* row = S + r * NPTS;
  const int t = threadIdx.x;   // 256
  double s = 0.0;
#pragma unroll
  for (int j = 0; j < 8; ++j) s += (double)row[t + j * 256];
  for (int off = 32; off > 0; off >>= 1) s += __shfl_down(s, off);
  __shared__ double ps[4];
  if ((t & 63) == 0) ps[t >> 6] = s;
  __syncthreads();
  if (t == 0) rs[r] = ps[0] + ps[1] + ps[2] + ps[3];
}

// ---------------- greedy traversal: ONE WAVE per batch, no barriers, no LDS ----------------
// Lane l owns cols {c*256 + 4*l + s : c in [0,8), s in [0,4)} — 8 coalesced float4 loads/step.
// Visited mask: 32 bits per lane (bit = c*4+s). Argmax: 6-level shuffle butterfly,
// first-index tie-break (within-lane iteration order is strictly increasing col).
__global__ __launch_bounds__(64) void traverse_k(const float* __restrict__ S,
                                                 const double* __restrict__ rs,
                                                 float* __restrict__ order_f, int cs) {
  const int ci = blockIdx.x;
  const int gb = cs + ci;
  const int lane = threadIdx.x;   // 64 threads = 1 wave

  // start = argmax_i rowsum (first-index tie-break)
  const double* rb = rs + (size_t)ci * NPTS;
  double dv = -1.0e300; int di = 0;
#pragma unroll
  for (int c = 0; c < 32; ++c) {
    int j = c * 64 + lane;
    double v = rb[j];
    if (v > dv) { dv = v; di = j; }
  }
  for (int off = 32; off > 0; off >>= 1) {
    double vo = __shfl_down(dv, off);
    int io = __shfl_down(di, off);
    if (vo > dv || (vo == dv && io < di)) { dv = vo; di = io; }
  }
  int cur = __shfl(di, 0);

  unsigned vis = 0;               // per-lane visited bits
  if (lane == ((cur >> 2) & 63)) vis |= 1u << (((cur >> 8) << 2) | (cur & 3));
  if (lane == 0) order_f[(size_t)gb * NPTS] = (float)cur;

  const float* Sb = S + (size_t)ci * NPTS * NPTS;

  for (int s = 1; s < NPTS; ++s) {
    const float4* row = (const float4*)(Sb + (size_t)cur * NPTS);
    float4 v[8];
#pragma unroll
    for (int c = 0; c < 8; ++c) v[c] = row[c * 64 + lane];

    float bv = -INFINITY; int bi = 0;
#pragma unroll
    for (int c = 0; c < 8; ++c) {
      const int base = c * 256 + 4 * lane;
      float x0 = (vis & (1u << (4 * c + 0))) ? -INFINITY : v[c].x;
      float x1 = (vis & (1u << (4 * c + 1))) ? -INFINITY : v[c].y;
      float x2 = (vis & (1u << (4 * c + 2))) ? -INFINITY : v[c].z;
      float x3 = (vis & (1u << (4 * c + 3))) ? -INFINITY : v[c].w;
      if (x0 > bv) { bv = x0; bi = base + 0; }
      if (x1 > bv) { bv = x1; bi = base + 1; }
      if (x2 > bv) { bv = x2; bi = base + 2; }
      if (x3 > bv) { bv = x3; bi = base + 3; }
    }
    for (int off = 32; off > 0; off >>= 1) {
      float vo = __shfl_down(bv, off);
      int io = __shfl_down(bi, off);
      if (vo > bv || (vo == bv && io < bi)) { bv = vo; bi = io; }
    }
    const int nxt = __shfl(bi, 0);
    if (lane == ((nxt >> 2) & 63)) vis |= 1u << (((nxt >> 8) << 2) | (nxt & 3));
    if (lane == 0) order_f[(size_t)gb * NPTS + s] = (float)nxt;
    cur = nxt;
  }
}

// ---------------- gather: reordered = features[order] ----------------
__global__ void gather_k(const float* __restrict__ feat, const float* __restrict__ order_f,
                         float* __restrict__ out) {
  const int bk = blockIdx.x;
  const int b = bk >> 11, k = bk & (NPTS - 1);
  const int idx = (int)order_f[(size_t)b * NPTS + k];
  const float4* src = (const float4*)(feat + ((size_t)b * NPTS + idx) * DIM);
  float4* dst = (float4*)(out + ((size_t)b * NPTS + k) * DIM);
  dst[threadIdx.x] = src[threadIdx.x];   // 192 threads x float4 = 768 floats
}

extern "C" void kernel_launch(void* const* d_in, const int* in_sizes, int n_in,
                              void* d_out, int out_size, void* d_ws, size_t ws_size,
                              hipStream_t stream) {
  const float* features = (const float*)d_in[0];
  const float* coords   = (const float*)d_in[1];
  float* out = (float*)d_out;
  float* order_f = out + (size_t)BATCH * NPTS * DIM;   // order stored as float values

  // ws per batch: rowsum (N*8) + S (N*N*4) + fn (N*D*4)
  const size_t per_b = (size_t)NPTS * 8 + (size_t)NPTS * NPTS * 4 + (size_t)NPTS * DIM * 4;
  int C = BATCH;
  while (C > 1 && per_b * (size_t)C > ws_size) C >>= 1;   // chunked fallback if ws is small

  char* wp = (char*)d_ws;
  double* rowsum = (double*)wp;
  float* S  = (float*)(wp + (size_t)C * NPTS * 8);
  float* fn = (float*)(wp + (size_t)C * NPTS * 8 + (size_t)C * NPTS * NPTS * 4);

  for (int cs = 0; cs < BATCH; cs += C) {
    normalize_k<<<dim3(C * NPTS), dim3(256), 0, stream>>>(features, fn, cs);
    gemm_k<<<dim3(16, 16, C), dim3(16, 16), 0, stream>>>(fn, coords, S, cs);
    rowsum_k<<<dim3(C * NPTS), dim3(256), 0, stream>>>(S, rowsum);
    traverse_k<<<dim3(C), dim3(64), 0, stream>>>(S, rowsum, order_f, cs);
  }
  gather_k<<<dim3(BATCH * NPTS), dim3(192), 0, stream>>>(features, order_f, out);
}

// Round 3
// 5020.361 us; speedup vs baseline: 1.4867x; 1.4867x over previous
//
#include <hip/hip_runtime.h>
#include <math.h>

#define BATCH 16
#define NPTS  2048
#define DIM   768
#define KC    16

// ---------------- normalize: fn = f / max(||f||,1e-12), fp64 norm ----------------
__global__ void normalize_k(const float* __restrict__ feat, float* __restrict__ fn, int cs) {
  const int rn = blockIdx.x;                 // ci*NPTS + n
  const int ci = rn >> 11, n = rn & (NPTS - 1);
  const float* src = feat + ((size_t)(cs + ci) * NPTS + n) * DIM;
  const int t = threadIdx.x;                 // 256 threads
  float f0 = src[t], f1 = src[t + 256], f2 = src[t + 512];
  double s = (double)f0 * (double)f0 + (double)f1 * (double)f1 + (double)f2 * (double)f2;
  for (int off = 32; off > 0; off >>= 1) s += __shfl_down(s, off);
  __shared__ double ps[4];
  __shared__ double rbc;
  const int lane = t & 63, wid = t >> 6;
  if (lane == 0) ps[wid] = s;
  __syncthreads();
  if (t == 0) {
    double tot = ps[0] + ps[1] + ps[2] + ps[3];
    rbc = fmax(sqrt(tot), 1e-12);
  }
  __syncthreads();
  const double r = rbc;
  float* dst = fn + ((size_t)ci * NPTS + n) * DIM;
  dst[t]       = (float)((double)f0 / r);
  dst[t + 256] = (float)((double)f1 / r);
  dst[t + 512] = (float)((double)f2 / r);
}

// physical LDS column swizzle: logical col c -> c + 4*(c>>5); max 139, width 144.
// 8-aligned groups never cross a 32 boundary, so 8-float runs stay contiguous.
__device__ __forceinline__ int pcol(int c) { return c + 4 * (c >> 5); }

// ---------------- similarity: S = fn.fn^T (fp64 acc) + 0.5*exp(-d2/1e4) ----------------
// Upper-triangle 128x128 tiles only (bx<=by); mirror_k fills the rest.
// 256 threads (16x16), 8x8 fp64 micro-tile, fp32 LDS tiles (exact cvt to fp64),
// register double-buffered global staging.
__global__ __launch_bounds__(256, 2) void gemm_k(const float* __restrict__ fn,
                                                 const float* __restrict__ coords,
                                                 float* __restrict__ S, int cs) {
  if (blockIdx.x > blockIdx.y) return;       // symmetry: skip strictly-lower tiles
  const int ci = blockIdx.z;
  const int i0 = blockIdx.x * 128;
  const int j0 = blockIdx.y * 128;
  const int tx = threadIdx.x, ty = threadIdx.y;
  const int tid = ty * 16 + tx;
  __shared__ float Af[KC][144];   // [k][pcol(i)]
  __shared__ float Bf[KC][144];   // [k][pcol(j)]
  double acc[8][8];
#pragma unroll
  for (int r = 0; r < 8; ++r)
#pragma unroll
    for (int c = 0; c < 8; ++c) acc[r][c] = 0.0;

  const float* fb = fn + (size_t)ci * NPTS * DIM;
  const int row = tid >> 1;        // 0..127 (staging row)
  const int half = tid & 1;        // which 8-wide k slice
  const int kk = half * 8;
  const int prow = pcol(row);
  const float* apBase = fb + (size_t)(i0 + row) * DIM + half * 8;
  const float* bpBase = fb + (size_t)(j0 + row) * DIM + half * 8;

  // prefetch chunk 0
  float4 pa0 = *(const float4*)(apBase);
  float4 pa1 = *(const float4*)(apBase + 4);
  float4 pb0 = *(const float4*)(bpBase);
  float4 pb1 = *(const float4*)(bpBase + 4);

  const int pcA = pcol(8 * ty);
  const int pcB = pcol(8 * tx);

  for (int k0 = 0; k0 < DIM; k0 += KC) {
    __syncthreads();   // previous chunk's readers done
    Af[kk + 0][prow] = pa0.x; Af[kk + 1][prow] = pa0.y; Af[kk + 2][prow] = pa0.z; Af[kk + 3][prow] = pa0.w;
    Af[kk + 4][prow] = pa1.x; Af[kk + 5][prow] = pa1.y; Af[kk + 6][prow] = pa1.z; Af[kk + 7][prow] = pa1.w;
    Bf[kk + 0][prow] = pb0.x; Bf[kk + 1][prow] = pb0.y; Bf[kk + 2][prow] = pb0.z; Bf[kk + 3][prow] = pb0.w;
    Bf[kk + 4][prow] = pb1.x; Bf[kk + 5][prow] = pb1.y; Bf[kk + 6][prow] = pb1.z; Bf[kk + 7][prow] = pb1.w;
    __syncthreads();
    if (k0 + KC < DIM) {           // prefetch next chunk; overlaps compute below
      pa0 = *(const float4*)(apBase + k0 + KC);
      pa1 = *(const float4*)(apBase + k0 + KC + 4);
      pb0 = *(const float4*)(bpBase + k0 + KC);
      pb1 = *(const float4*)(bpBase + k0 + KC + 4);
    }
#pragma unroll
    for (int k = 0; k < KC; ++k) {
      float4 fa0 = *(const float4*)&Af[k][pcA];
      float4 fa1 = *(const float4*)&Af[k][pcA + 4];
      float4 fb0 = *(const float4*)&Bf[k][pcB];
      float4 fb1 = *(const float4*)&Bf[k][pcB + 4];
      double a[8], b[8];
      a[0] = fa0.x; a[1] = fa0.y; a[2] = fa0.z; a[3] = fa0.w;
      a[4] = fa1.x; a[5] = fa1.y; a[6] = fa1.z; a[7] = fa1.w;
      b[0] = fb0.x; b[1] = fb0.y; b[2] = fb0.z; b[3] = fb0.w;
      b[4] = fb1.x; b[5] = fb1.y; b[6] = fb1.z; b[7] = fb1.w;
#pragma unroll
      for (int r = 0; r < 8; ++r)
#pragma unroll
        for (int c = 0; c < 8; ++c) acc[r][c] = fma(a[r], b[c], acc[r][c]);
    }
  }

  // epilogue: + 0.5 * exp(-sq_dist/10000), exp via 4th-order Taylor (x<=2e-4, err ~1e-20)
  const float* cb = coords + (size_t)(cs + ci) * NPTS * 2;
  double cxi[8], cyi[8], cxj[8], cyj[8];
#pragma unroll
  for (int r = 0; r < 8; ++r) { float2 p = *(const float2*)(cb + 2 * (i0 + 8 * ty + r)); cxi[r] = p.x; cyi[r] = p.y; }
#pragma unroll
  for (int c = 0; c < 8; ++c) { float2 p = *(const float2*)(cb + 2 * (j0 + 8 * tx + c)); cxj[c] = p.x; cyj[c] = p.y; }
  float* Sb = S + (size_t)ci * NPTS * NPTS;
#pragma unroll
  for (int r = 0; r < 8; ++r) {
    float o[8];
#pragma unroll
    for (int c = 0; c < 8; ++c) {
      double dx = cxi[r] - cxj[c], dy = cyi[r] - cyj[c];
      double x = (dx * dx + dy * dy) * (1.0 / 10000.0);
      double e = 1.0 - x * (1.0 - x * (0.5 - x * ((1.0 / 6.0) - x * (1.0 / 24.0))));
      o[c] = (float)(acc[r][c] + 0.5 * e);
    }
    float* orow = Sb + (size_t)(i0 + 8 * ty + r) * NPTS + j0 + 8 * tx;
    ((float4*)orow)[0] = make_float4(o[0], o[1], o[2], o[3]);
    ((float4*)orow)[1] = make_float4(o[4], o[5], o[6], o[7]);
  }
}

// ---------------- mirror: fill strictly-lower 128-blocks from upper triangle ----------------
// 64x64 tiles, coalesced read + coalesced write via LDS transpose.
__global__ __launch_bounds__(256) void mirror_k(float* __restrict__ S) {
  const int Cb = blockIdx.x, Rb = blockIdx.y;   // dest 64-tile coords
  if ((Rb >> 1) <= (Cb >> 1)) return;           // only strictly-lower 128-blocks
  float* Sb = S + (size_t)blockIdx.z * NPTS * NPTS;
  __shared__ float t[64][65];
  const int lane = threadIdx.x & 63, w = threadIdx.x >> 6;
#pragma unroll
  for (int p = 0; p < 16; ++p) {
    const int r = w + 4 * p;
    t[r][lane] = Sb[(size_t)(Cb * 64 + r) * NPTS + Rb * 64 + lane];   // source (upper) tile
  }
  __syncthreads();
#pragma unroll
  for (int p = 0; p < 16; ++p) {
    const int r = w + 4 * p;
    Sb[(size_t)(Rb * 64 + r) * NPTS + Cb * 64 + lane] = t[lane][r];   // transposed dest
  }
}

// ---------------- row sums (fp64) for start-node selection ----------------
__global__ void rowsum_k(const float* __restrict__ S, double* __restrict__ rs) {
  const size_t r = blockIdx.x;
  const float* row = S + r * NPTS;
  const int t = threadIdx.x;   // 256
  double s = 0.0;
#pragma unroll
  for (int j = 0; j < 8; ++j) s += (double)row[t + j * 256];
  for (int off = 32; off > 0; off >>= 1) s += __shfl_down(s, off);
  __shared__ double ps[4];
  if ((t & 63) == 0) ps[t >> 6] = s;
  __syncthreads();
  if (t == 0) rs[r] = ps[0] + ps[1] + ps[2] + ps[3];
}

// ---------------- greedy traversal: ONE WAVE per batch, no barriers, no LDS ----------------
__global__ __launch_bounds__(64) void traverse_k(const float* __restrict__ S,
                                                 const double* __restrict__ rs,
                                                 float* __restrict__ order_f, int cs) {
  const int ci = blockIdx.x;
  const int gb = cs + ci;
  const int lane = threadIdx.x;   // 64 threads = 1 wave

  const double* rb = rs + (size_t)ci * NPTS;
  double dv = -1.0e300; int di = 0;
#pragma unroll
  for (int c = 0; c < 32; ++c) {
    int j = c * 64 + lane;
    double v = rb[j];
    if (v > dv) { dv = v; di = j; }
  }
  for (int off = 32; off > 0; off >>= 1) {
    double vo = __shfl_down(dv, off);
    int io = __shfl_down(di, off);
    if (vo > dv || (vo == dv && io < di)) { dv = vo; di = io; }
  }
  int cur = __shfl(di, 0);

  unsigned vis = 0;               // per-lane visited bits (bit = c*4+s for col c*256+4*lane+s)
  if (lane == ((cur >> 2) & 63)) vis |= 1u << (((cur >> 8) << 2) | (cur & 3));
  if (lane == 0) order_f[(size_t)gb * NPTS] = (float)cur;

  const float* Sb = S + (size_t)ci * NPTS * NPTS;

  for (int s = 1; s < NPTS; ++s) {
    const float4* row = (const float4*)(Sb + (size_t)cur * NPTS);
    float4 v[8];
#pragma unroll
    for (int c = 0; c < 8; ++c) v[c] = row[c * 64 + lane];

    float bv = -INFINITY; int bi = 0;
#pragma unroll
    for (int c = 0; c < 8; ++c) {
      const int base = c * 256 + 4 * lane;
      float x0 = (vis & (1u << (4 * c + 0))) ? -INFINITY : v[c].x;
      float x1 = (vis & (1u << (4 * c + 1))) ? -INFINITY : v[c].y;
      float x2 = (vis & (1u << (4 * c + 2))) ? -INFINITY : v[c].z;
      float x3 = (vis & (1u << (4 * c + 3))) ? -INFINITY : v[c].w;
      if (x0 > bv) { bv = x0; bi = base + 0; }
      if (x1 > bv) { bv = x1; bi = base + 1; }
      if (x2 > bv) { bv = x2; bi = base + 2; }
      if (x3 > bv) { bv = x3; bi = base + 3; }
    }
    for (int off = 32; off > 0; off >>= 1) {
      float vo = __shfl_down(bv, off);
      int io = __shfl_down(bi, off);
      if (vo > bv || (vo == bv && io < bi)) { bv = vo; bi = io; }
    }
    const int nxt = __shfl(bi, 0);
    if (lane == ((nxt >> 2) & 63)) vis |= 1u << (((nxt >> 8) << 2) | (nxt & 3));
    if (lane == 0) order_f[(size_t)gb * NPTS + s] = (float)nxt;
    cur = nxt;
  }
}

// ---------------- gather: reordered = features[order] ----------------
__global__ void gather_k(const float* __restrict__ feat, const float* __restrict__ order_f,
                         float* __restrict__ out) {
  const int bk = blockIdx.x;
  const int b = bk >> 11, k = bk & (NPTS - 1);
  const int idx = (int)order_f[(size_t)b * NPTS + k];
  const float4* src = (const float4*)(feat + ((size_t)b * NPTS + idx) * DIM);
  float4* dst = (float4*)(out + ((size_t)b * NPTS + k) * DIM);
  dst[threadIdx.x] = src[threadIdx.x];   // 192 threads x float4 = 768 floats
}

extern "C" void kernel_launch(void* const* d_in, const int* in_sizes, int n_in,
                              void* d_out, int out_size, void* d_ws, size_t ws_size,
                              hipStream_t stream) {
  const float* features = (const float*)d_in[0];
  const float* coords   = (const float*)d_in[1];
  float* out = (float*)d_out;
  float* order_f = out + (size_t)BATCH * NPTS * DIM;   // order stored as float values

  // ws per batch: rowsum (N*8) + S (N*N*4) + fn (N*D*4)
  const size_t per_b = (size_t)NPTS * 8 + (size_t)NPTS * NPTS * 4 + (size_t)NPTS * DIM * 4;
  int C = BATCH;
  while (C > 1 && per_b * (size_t)C > ws_size) C >>= 1;   // chunked fallback if ws is small

  char* wp = (char*)d_ws;
  double* rowsum = (double*)wp;
  float* S  = (float*)(wp + (size_t)C * NPTS * 8);
  float* fn = (float*)(wp + (size_t)C * NPTS * 8 + (size_t)C * NPTS * NPTS * 4);

  for (int cs = 0; cs < BATCH; cs += C) {
    normalize_k<<<dim3(C * NPTS), dim3(256), 0, stream>>>(features, fn, cs);
    gemm_k<<<dim3(16, 16, C), dim3(16, 16), 0, stream>>>(fn, coords, S, cs);
    mirror_k<<<dim3(32, 32, C), dim3(256), 0, stream>>>(S);
    rowsum_k<<<dim3(C * NPTS), dim3(256), 0, stream>>>(S, rowsum);
    traverse_k<<<dim3(C), dim3(64), 0, stream>>>(S, rowsum, order_f, cs);
  }
  gather_k<<<dim3(BATCH * NPTS), dim3(192), 0, stream>>>(features, order_f, out);
}

// Round 4
// 3753.033 us; speedup vs baseline: 1.9887x; 1.3377x over previous
//
#include <hip/hip_runtime.h>
#include <math.h>

#define BATCH 16
#define NPTS  2048
#define DIM   768
#define KC    16

// ---------------- normalize: fn = f / max(||f||,1e-12), fp64 norm ----------------
__global__ void normalize_k(const float* __restrict__ feat, float* __restrict__ fn, int cs) {
  const int rn = blockIdx.x;                 // ci*NPTS + n
  const int ci = rn >> 11, n = rn & (NPTS - 1);
  const float* src = feat + ((size_t)(cs + ci) * NPTS + n) * DIM;
  const int t = threadIdx.x;                 // 256 threads
  float f0 = src[t], f1 = src[t + 256], f2 = src[t + 512];
  double s = (double)f0 * (double)f0 + (double)f1 * (double)f1 + (double)f2 * (double)f2;
  for (int off = 32; off > 0; off >>= 1) s += __shfl_down(s, off);
  __shared__ double ps[4];
  __shared__ double rbc;
  const int lane = t & 63, wid = t >> 6;
  if (lane == 0) ps[wid] = s;
  __syncthreads();
  if (t == 0) {
    double tot = ps[0] + ps[1] + ps[2] + ps[3];
    rbc = fmax(sqrt(tot), 1e-12);
  }
  __syncthreads();
  const double r = rbc;
  float* dst = fn + ((size_t)ci * NPTS + n) * DIM;
  dst[t]       = (float)((double)f0 / r);
  dst[t + 256] = (float)((double)f1 / r);
  dst[t + 512] = (float)((double)f2 / r);
}

// physical LDS column swizzle: logical col c -> c + 4*(c>>5); max 139, width 144.
__device__ __forceinline__ int pcol(int c) { return c + 4 * (c >> 5); }

// ---------------- similarity: S = fn.fn^T (fp64 acc) + 0.5*exp(-d2/1e4) ----------------
__global__ __launch_bounds__(256, 2) void gemm_k(const float* __restrict__ fn,
                                                 const float* __restrict__ coords,
                                                 float* __restrict__ S, int cs) {
  if (blockIdx.x > blockIdx.y) return;       // symmetry: skip strictly-lower tiles
  const int ci = blockIdx.z;
  const int i0 = blockIdx.x * 128;
  const int j0 = blockIdx.y * 128;
  const int tx = threadIdx.x, ty = threadIdx.y;
  const int tid = ty * 16 + tx;
  __shared__ float Af[KC][144];
  __shared__ float Bf[KC][144];
  double acc[8][8];
#pragma unroll
  for (int r = 0; r < 8; ++r)
#pragma unroll
    for (int c = 0; c < 8; ++c) acc[r][c] = 0.0;

  const float* fb = fn + (size_t)ci * NPTS * DIM;
  const int row = tid >> 1;
  const int half = tid & 1;
  const int kk = half * 8;
  const int prow = pcol(row);
  const float* apBase = fb + (size_t)(i0 + row) * DIM + half * 8;
  const float* bpBase = fb + (size_t)(j0 + row) * DIM + half * 8;

  float4 pa0 = *(const float4*)(apBase);
  float4 pa1 = *(const float4*)(apBase + 4);
  float4 pb0 = *(const float4*)(bpBase);
  float4 pb1 = *(const float4*)(bpBase + 4);

  const int pcA = pcol(8 * ty);
  const int pcB = pcol(8 * tx);

  for (int k0 = 0; k0 < DIM; k0 += KC) {
    __syncthreads();
    Af[kk + 0][prow] = pa0.x; Af[kk + 1][prow] = pa0.y; Af[kk + 2][prow] = pa0.z; Af[kk + 3][prow] = pa0.w;
    Af[kk + 4][prow] = pa1.x; Af[kk + 5][prow] = pa1.y; Af[kk + 6][prow] = pa1.z; Af[kk + 7][prow] = pa1.w;
    Bf[kk + 0][prow] = pb0.x; Bf[kk + 1][prow] = pb0.y; Bf[kk + 2][prow] = pb0.z; Bf[kk + 3][prow] = pb0.w;
    Bf[kk + 4][prow] = pb1.x; Bf[kk + 5][prow] = pb1.y; Bf[kk + 6][prow] = pb1.z; Bf[kk + 7][prow] = pb1.w;
    __syncthreads();
    if (k0 + KC < DIM) {
      pa0 = *(const float4*)(apBase + k0 + KC);
      pa1 = *(const float4*)(apBase + k0 + KC + 4);
      pb0 = *(const float4*)(bpBase + k0 + KC);
      pb1 = *(const float4*)(bpBase + k0 + KC + 4);
    }
#pragma unroll
    for (int k = 0; k < KC; ++k) {
      float4 fa0 = *(const float4*)&Af[k][pcA];
      float4 fa1 = *(const float4*)&Af[k][pcA + 4];
      float4 fb0 = *(const float4*)&Bf[k][pcB];
      float4 fb1 = *(const float4*)&Bf[k][pcB + 4];
      double a[8], b[8];
      a[0] = fa0.x; a[1] = fa0.y; a[2] = fa0.z; a[3] = fa0.w;
      a[4] = fa1.x; a[5] = fa1.y; a[6] = fa1.z; a[7] = fa1.w;
      b[0] = fb0.x; b[1] = fb0.y; b[2] = fb0.z; b[3] = fb0.w;
      b[4] = fb1.x; b[5] = fb1.y; b[6] = fb1.z; b[7] = fb1.w;
#pragma unroll
      for (int r = 0; r < 8; ++r)
#pragma unroll
        for (int c = 0; c < 8; ++c) acc[r][c] = fma(a[r], b[c], acc[r][c]);
    }
  }

  const float* cb = coords + (size_t)(cs + ci) * NPTS * 2;
  double cxi[8], cyi[8], cxj[8], cyj[8];
#pragma unroll
  for (int r = 0; r < 8; ++r) { float2 p = *(const float2*)(cb + 2 * (i0 + 8 * ty + r)); cxi[r] = p.x; cyi[r] = p.y; }
#pragma unroll
  for (int c = 0; c < 8; ++c) { float2 p = *(const float2*)(cb + 2 * (j0 + 8 * tx + c)); cxj[c] = p.x; cyj[c] = p.y; }
  float* Sb = S + (size_t)ci * NPTS * NPTS;
#pragma unroll
  for (int r = 0; r < 8; ++r) {
    float o[8];
#pragma unroll
    for (int c = 0; c < 8; ++c) {
      double dx = cxi[r] - cxj[c], dy = cyi[r] - cyj[c];
      double x = (dx * dx + dy * dy) * (1.0 / 10000.0);
      double e = 1.0 - x * (1.0 - x * (0.5 - x * ((1.0 / 6.0) - x * (1.0 / 24.0))));
      o[c] = (float)(acc[r][c] + 0.5 * e);
    }
    float* orow = Sb + (size_t)(i0 + 8 * ty + r) * NPTS + j0 + 8 * tx;
    ((float4*)orow)[0] = make_float4(o[0], o[1], o[2], o[3]);
    ((float4*)orow)[1] = make_float4(o[4], o[5], o[6], o[7]);
  }
}

// ---------------- mirror: fill strictly-lower 128-blocks from upper triangle ----------------
__global__ __launch_bounds__(256) void mirror_k(float* __restrict__ S) {
  const int Cb = blockIdx.x, Rb = blockIdx.y;
  if ((Rb >> 1) <= (Cb >> 1)) return;
  float* Sb = S + (size_t)blockIdx.z * NPTS * NPTS;
  __shared__ float t[64][65];
  const int lane = threadIdx.x & 63, w = threadIdx.x >> 6;
#pragma unroll
  for (int p = 0; p < 16; ++p) {
    const int r = w + 4 * p;
    t[r][lane] = Sb[(size_t)(Cb * 64 + r) * NPTS + Rb * 64 + lane];
  }
  __syncthreads();
#pragma unroll
  for (int p = 0; p < 16; ++p) {
    const int r = w + 4 * p;
    Sb[(size_t)(Rb * 64 + r) * NPTS + Cb * 64 + lane] = t[lane][r];
  }
}

// ---------------- monotone fp32 key: a > b (float) <=> mono(a) > mono(b) (uint) ----------------
__device__ __forceinline__ unsigned mono(float f) {
  unsigned u = __float_as_uint(f);
  return (u & 0x80000000u) ? ~u : (u | 0x80000000u);
}

// ---------------- DPP wave-64 reductions (rocPRIM gfx9 pattern), result broadcast ----------------
#define DPP_RED_STEP(OP, X, CTRL, RMASK) \
  X = OP(X, (unsigned)__builtin_amdgcn_update_dpp((int)(X), (int)(X), CTRL, RMASK, 0xf, false))
__device__ __forceinline__ unsigned umaxu(unsigned a, unsigned b) { return a > b ? a : b; }
__device__ __forceinline__ unsigned uminu(unsigned a, unsigned b) { return a < b ? a : b; }

__device__ __forceinline__ unsigned wave_max_bcast(unsigned x) {
  DPP_RED_STEP(umaxu, x, 0x111, 0xf);  // row_shr:1
  DPP_RED_STEP(umaxu, x, 0x112, 0xf);  // row_shr:2
  DPP_RED_STEP(umaxu, x, 0x114, 0xf);  // row_shr:4
  DPP_RED_STEP(umaxu, x, 0x118, 0xf);  // row_shr:8
  DPP_RED_STEP(umaxu, x, 0x142, 0xa);  // row_bcast:15 -> rows 1,3
  DPP_RED_STEP(umaxu, x, 0x143, 0xc);  // row_bcast:31 -> rows 2,3
  return (unsigned)__builtin_amdgcn_readlane((int)x, 63);
}
__device__ __forceinline__ unsigned wave_min_bcast(unsigned x) {
  DPP_RED_STEP(uminu, x, 0x111, 0xf);
  DPP_RED_STEP(uminu, x, 0x112, 0xf);
  DPP_RED_STEP(uminu, x, 0x114, 0xf);
  DPP_RED_STEP(uminu, x, 0x118, 0xf);
  DPP_RED_STEP(uminu, x, 0x142, 0xa);
  DPP_RED_STEP(uminu, x, 0x143, 0xc);
  return (unsigned)__builtin_amdgcn_readlane((int)x, 63);
}

// ---------------- cand_k: per-row lane-top-2 candidates + tau + fp64 rowsum ----------------
// One wave per row. Lane owns cols {c*256 + 4*lane + s}. Candidates: lane's top-2 (val,idx),
// idx ascending among equal vals. tau = wave-max of per-lane 3rd max (bound on non-candidates).
__global__ __launch_bounds__(64) void cand_k(const float* __restrict__ S,
                                             float4* __restrict__ cand,
                                             unsigned* __restrict__ montau,
                                             double* __restrict__ rs) {
  const size_t r = blockIdx.x;               // ci*NPTS + row
  const float* row = S + r * NPTS;
  const int lane = threadIdx.x;
  float v0 = -INFINITY, v1 = -INFINITY, v2 = -INFINITY;
  int i0 = 0, i1 = 0;
  double sum = 0.0;
#pragma unroll
  for (int c = 0; c < 8; ++c) {
    float4 q = ((const float4*)row)[c * 64 + lane];
    const int base = c * 256 + 4 * lane;
    float xs[4] = {q.x, q.y, q.z, q.w};
#pragma unroll
    for (int s = 0; s < 4; ++s) {
      float x = xs[s];
      sum += (double)x;
      if (x > v1) {
        if (x > v0) { v2 = v1; v1 = v0; i1 = i0; v0 = x; i0 = base + s; }
        else        { v2 = v1; v1 = x; i1 = base + s; }
      } else if (x > v2) v2 = x;
    }
  }
  cand[r * 64 + lane] = make_float4(v0, __int_as_float(i0), v1, __int_as_float(i1));
  float t = v2;
  for (int off = 32; off > 0; off >>= 1) {
    t = fmaxf(t, __shfl_down(t, off));
    sum += __shfl_down(sum, off);
  }
  if (lane == 0) { montau[r] = mono(t); rs[r] = sum; }
}

// ---------------- greedy traversal: one wave per batch, candidate fast path ----------------
__global__ __launch_bounds__(64) void traverse_k(const float* __restrict__ S,
                                                 const float4* __restrict__ cand,
                                                 const unsigned* __restrict__ montau,
                                                 const double* __restrict__ rs,
                                                 float* __restrict__ order_f, int cs) {
  const int ci = blockIdx.x;
  const int gb = cs + ci;
  const int lane = threadIdx.x;

  // start = argmax_i rowsum (fp64, first-index tie-break) — one-time, shuffle reduce
  const double* rb = rs + (size_t)ci * NPTS;
  double dv = -1.0e300; int di = 0;
#pragma unroll
  for (int c = 0; c < 32; ++c) {
    int j = c * 64 + lane;
    double v = rb[j];
    if (v > dv) { dv = v; di = j; }
  }
  for (int off = 32; off > 0; off >>= 1) {
    double vo = __shfl_down(dv, off);
    int io = __shfl_down(di, off);
    if (vo > dv || (vo == dv && io < di)) { dv = vo; di = io; }
  }
  int cur = __shfl(di, 0);

  // visited state: vis = traverse-layout bits (col c*256+4*lane+s -> bit 4c+s),
  //                visw = word-layout (lane L owns cols [32L,32L+31])
  unsigned vis = 0, visw = 0;
  if (lane == ((cur >> 2) & 63)) vis |= 1u << (((cur >> 8) << 2) | (cur & 3));
  if (lane == (cur >> 5))        visw |= 1u << (cur & 31);
  if (lane == 0) order_f[(size_t)gb * NPTS] = (float)cur;

  const float*  Sb = S + (size_t)ci * NPTS * NPTS;
  const float4* cb = cand + (size_t)ci * NPTS * 64;
  const unsigned* tb = montau + (size_t)ci * NPTS;

  for (int s = 1; s < NPTS; ++s) {
    // ---- fast path: lane-top-2 candidates ----
    const float4 cq = cb[(size_t)cur * 64 + lane];
    const unsigned ktau = tb[cur];
    unsigned k0 = mono(cq.x), k1 = mono(cq.z);
    int i0 = __float_as_int(cq.y), i1 = __float_as_int(cq.w);
    unsigned w0 = (unsigned)__shfl((int)visw, i0 >> 5);
    unsigned w1 = (unsigned)__shfl((int)visw, i1 >> 5);
    unsigned ka = ((w0 >> (i0 & 31)) & 1u) ? 0u : k0;
    unsigned kb = ((w1 >> (i1 & 31)) & 1u) ? 0u : k1;
    unsigned kl, il;
    if (kb > ka) { kl = kb; il = (unsigned)i1; } else { kl = ka; il = (unsigned)i0; }
    const unsigned kmax = wave_max_bcast(kl);
    int nxt;
    if (kmax > ktau) {
      // exact: best unvisited candidate strictly beats every non-candidate value
      unsigned cidx = (kl == kmax) ? il : 0xFFFFFFFFu;
      nxt = (int)wave_min_bcast(cidx);
    } else {
      // ---- fallback: full masked row scan ----
      const float4* rowp = (const float4*)(Sb + (size_t)cur * NPTS);
      float4 v[8];
#pragma unroll
      for (int c = 0; c < 8; ++c) v[c] = rowp[c * 64 + lane];
      float bv = -INFINITY; int bi = 0;
#pragma unroll
      for (int c = 0; c < 8; ++c) {
        const int base = c * 256 + 4 * lane;
        float x0 = (vis & (1u << (4 * c + 0))) ? -INFINITY : v[c].x;
        float x1 = (vis & (1u << (4 * c + 1))) ? -INFINITY : v[c].y;
        float x2 = (vis & (1u << (4 * c + 2))) ? -INFINITY : v[c].z;
        float x3 = (vis & (1u << (4 * c + 3))) ? -INFINITY : v[c].w;
        if (x0 > bv) { bv = x0; bi = base + 0; }
        if (x1 > bv) { bv = x1; bi = base + 1; }
        if (x2 > bv) { bv = x2; bi = base + 2; }
        if (x3 > bv) { bv = x3; bi = base + 3; }
      }
      unsigned klf = mono(bv);
      const unsigned kmaxf = wave_max_bcast(klf);
      unsigned cidx = (klf == kmaxf) ? (unsigned)bi : 0xFFFFFFFFu;
      nxt = (int)wave_min_bcast(cidx);
    }
    if (lane == ((nxt >> 2) & 63)) vis |= 1u << (((nxt >> 8) << 2) | (nxt & 3));
    if (lane == (nxt >> 5))        visw |= 1u << (nxt & 31);
    if (lane == 0) order_f[(size_t)gb * NPTS + s] = (float)nxt;
    cur = nxt;
  }
}

// ---------------- gather: reordered = features[order] ----------------
__global__ void gather_k(const float* __restrict__ feat, const float* __restrict__ order_f,
                         float* __restrict__ out) {
  const int bk = blockIdx.x;
  const int b = bk >> 11, k = bk & (NPTS - 1);
  const int idx = (int)order_f[(size_t)b * NPTS + k];
  const float4* src = (const float4*)(feat + ((size_t)b * NPTS + idx) * DIM);
  float4* dst = (float4*)(out + ((size_t)b * NPTS + k) * DIM);
  dst[threadIdx.x] = src[threadIdx.x];
}

extern "C" void kernel_launch(void* const* d_in, const int* in_sizes, int n_in,
                              void* d_out, int out_size, void* d_ws, size_t ws_size,
                              hipStream_t stream) {
  const float* features = (const float*)d_in[0];
  const float* coords   = (const float*)d_in[1];
  float* out = (float*)d_out;
  float* order_f = out + (size_t)BATCH * NPTS * DIM;

  // ws per batch: rs (N*8) + montau (N*4) + S (N*N*4) + fn (N*D*4) + cand (N*64*16)
  const size_t per_b = (size_t)NPTS * 8 + (size_t)NPTS * 4 + (size_t)NPTS * NPTS * 4 +
                       (size_t)NPTS * DIM * 4 + (size_t)NPTS * 64 * 16;
  int C = BATCH;
  while (C > 1 && per_b * (size_t)C > ws_size) C >>= 1;

  char* wp = (char*)d_ws;
  double*   rowsum = (double*)wp;                 wp += (size_t)C * NPTS * 8;
  unsigned* mtau   = (unsigned*)wp;               wp += (size_t)C * NPTS * 4;
  float*    S      = (float*)wp;                  wp += (size_t)C * NPTS * NPTS * 4;
  float*    fn     = (float*)wp;                  wp += (size_t)C * NPTS * DIM * 4;
  float4*   cand   = (float4*)wp;

  for (int cs = 0; cs < BATCH; cs += C) {
    normalize_k<<<dim3(C * NPTS), dim3(256), 0, stream>>>(features, fn, cs);
    gemm_k<<<dim3(16, 16, C), dim3(16, 16), 0, stream>>>(fn, coords, S, cs);
    mirror_k<<<dim3(32, 32, C), dim3(256), 0, stream>>>(S);
    cand_k<<<dim3(C * NPTS), dim3(64), 0, stream>>>(S, cand, mtau, rowsum);
    traverse_k<<<dim3(C), dim3(64), 0, stream>>>(S, cand, mtau, rowsum, order_f, cs);
  }
  gather_k<<<dim3(BATCH * NPTS), dim3(192), 0, stream>>>(features, order_f, out);
}

// Round 6
// 3327.182 us; speedup vs baseline: 2.2432x; 1.1280x over previous
//
#include <hip/hip_runtime.h>
#include <math.h>

#define BATCH 16
#define NPTS  2048
#define DIM   768
#define KC    16

typedef double d4 __attribute__((ext_vector_type(4)));

// ---------------- normalize: fn = f / max(||f||,1e-12), fp64 norm ----------------
__global__ void normalize_k(const float* __restrict__ feat, float* __restrict__ fn, int cs) {
  const int rn = blockIdx.x;                 // ci*NPTS + n
  const int ci = rn >> 11, n = rn & (NPTS - 1);
  const float* src = feat + ((size_t)(cs + ci) * NPTS + n) * DIM;
  const int t = threadIdx.x;                 // 256 threads
  float f0 = src[t], f1 = src[t + 256], f2 = src[t + 512];
  double s = (double)f0 * (double)f0 + (double)f1 * (double)f1 + (double)f2 * (double)f2;
  for (int off = 32; off > 0; off >>= 1) s += __shfl_down(s, off);
  __shared__ double ps[4];
  __shared__ double rbc;
  const int lane = t & 63, wid = t >> 6;
  if (lane == 0) ps[wid] = s;
  __syncthreads();
  if (t == 0) {
    double tot = ps[0] + ps[1] + ps[2] + ps[3];
    rbc = fmax(sqrt(tot), 1e-12);
  }
  __syncthreads();
  const double r = rbc;
  float* dst = fn + ((size_t)ci * NPTS + n) * DIM;
  dst[t]       = (float)((double)f0 / r);
  dst[t + 256] = (float)((double)f1 / r);
  dst[t + 512] = (float)((double)f2 / r);
}

// ---------------- similarity: S = fn.fn^T (fp64 MFMA) + 0.5*exp(-d2/1e4) ----------------
// Upper-triangle 128x128 tiles (bx<=by); mirror_k fills the rest.
// 4 waves, each owns a 64x64 quadrant = 4x4 grid of 16x16 mfma tiles.
// Operands: A[m=lane&15][k=lane>>4], B[k=lane>>4][n=lane&15].
// C/D layout is PROBED at runtime (f64 layout unverified on gfx950; probes make
// the epilogue correct under any row/col/reg permutation of the C/D mapping).
__global__ __launch_bounds__(256, 2) void gemm_k(const float* __restrict__ fn,
                                                 const float* __restrict__ coords,
                                                 float* __restrict__ S, int cs) {
  if (blockIdx.x > blockIdx.y) return;       // symmetry: skip strictly-lower tiles
  const int ci = blockIdx.z;
  const int i0 = blockIdx.x * 128;
  const int j0 = blockIdx.y * 128;
  const int tid  = threadIdx.x;              // 256
  const int lane = tid & 63, w = tid >> 6;
  const int wr = (w >> 1) * 64, wc = (w & 1) * 64;   // wave quadrant
  const int lo = lane & 15, quad = lane >> 4;

  __shared__ double Ad[KC][131];   // [k][i]
  __shared__ double Bd[KC][131];   // [k][j]

  d4 acc[4][4];
#pragma unroll
  for (int tr = 0; tr < 4; ++tr)
#pragma unroll
    for (int tc = 0; tc < 4; ++tc) acc[tr][tc] = (d4){0.0, 0.0, 0.0, 0.0};

  const float* fb = fn + (size_t)ci * NPTS * DIM;
  const int row  = tid >> 1;       // staging row 0..127
  const int half = tid & 1;
  const int kk0  = half * 8;
  const float* apBase = fb + (size_t)(i0 + row) * DIM + half * 8;
  const float* bpBase = fb + (size_t)(j0 + row) * DIM + half * 8;

  // prefetch chunk 0
  float4 pa0 = *(const float4*)(apBase);
  float4 pa1 = *(const float4*)(apBase + 4);
  float4 pb0 = *(const float4*)(bpBase);
  float4 pb1 = *(const float4*)(bpBase + 4);

  for (int k0 = 0; k0 < DIM; k0 += KC) {
    __syncthreads();   // previous chunk's readers done
    Ad[kk0 + 0][row] = pa0.x; Ad[kk0 + 1][row] = pa0.y; Ad[kk0 + 2][row] = pa0.z; Ad[kk0 + 3][row] = pa0.w;
    Ad[kk0 + 4][row] = pa1.x; Ad[kk0 + 5][row] = pa1.y; Ad[kk0 + 6][row] = pa1.z; Ad[kk0 + 7][row] = pa1.w;
    Bd[kk0 + 0][row] = pb0.x; Bd[kk0 + 1][row] = pb0.y; Bd[kk0 + 2][row] = pb0.z; Bd[kk0 + 3][row] = pb0.w;
    Bd[kk0 + 4][row] = pb1.x; Bd[kk0 + 5][row] = pb1.y; Bd[kk0 + 6][row] = pb1.z; Bd[kk0 + 7][row] = pb1.w;
    __syncthreads();
    if (k0 + KC < DIM) {           // prefetch next chunk; overlaps MFMA below
      pa0 = *(const float4*)(apBase + k0 + KC);
      pa1 = *(const float4*)(apBase + k0 + KC + 4);
      pb0 = *(const float4*)(bpBase + k0 + KC);
      pb1 = *(const float4*)(bpBase + k0 + KC + 4);
    }
#pragma unroll
    for (int k4 = 0; k4 < KC; k4 += 4) {
      const int kk = k4 + quad;    // this lane's k index
      double a0 = Ad[kk][wr + lo +  0];
      double a1 = Ad[kk][wr + lo + 16];
      double a2 = Ad[kk][wr + lo + 32];
      double a3 = Ad[kk][wr + lo + 48];
      double b0 = Bd[kk][wc + lo +  0];
      double b1 = Bd[kk][wc + lo + 16];
      double b2 = Bd[kk][wc + lo + 32];
      double b3 = Bd[kk][wc + lo + 48];
      acc[0][0] = __builtin_amdgcn_mfma_f64_16x16x4f64(a0, b0, acc[0][0], 0, 0, 0);
      acc[0][1] = __builtin_amdgcn_mfma_f64_16x16x4f64(a0, b1, acc[0][1], 0, 0, 0);
      acc[0][2] = __builtin_amdgcn_mfma_f64_16x16x4f64(a0, b2, acc[0][2], 0, 0, 0);
      acc[0][3] = __builtin_amdgcn_mfma_f64_16x16x4f64(a0, b3, acc[0][3], 0, 0, 0);
      acc[1][0] = __builtin_amdgcn_mfma_f64_16x16x4f64(a1, b0, acc[1][0], 0, 0, 0);
      acc[1][1] = __builtin_amdgcn_mfma_f64_16x16x4f64(a1, b1, acc[1][1], 0, 0, 0);
      acc[1][2] = __builtin_amdgcn_mfma_f64_16x16x4f64(a1, b2, acc[1][2], 0, 0, 0);
      acc[1][3] = __builtin_amdgcn_mfma_f64_16x16x4f64(a1, b3, acc[1][3], 0, 0, 0);
      acc[2][0] = __builtin_amdgcn_mfma_f64_16x16x4f64(a2, b0, acc[2][0], 0, 0, 0);
      acc[2][1] = __builtin_amdgcn_mfma_f64_16x16x4f64(a2, b1, acc[2][1], 0, 0, 0);
      acc[2][2] = __builtin_amdgcn_mfma_f64_16x16x4f64(a2, b2, acc[2][2], 0, 0, 0);
      acc[2][3] = __builtin_amdgcn_mfma_f64_16x16x4f64(a2, b3, acc[2][3], 0, 0, 0);
      acc[3][0] = __builtin_amdgcn_mfma_f64_16x16x4f64(a3, b0, acc[3][0], 0, 0, 0);
      acc[3][1] = __builtin_amdgcn_mfma_f64_16x16x4f64(a3, b1, acc[3][1], 0, 0, 0);
      acc[3][2] = __builtin_amdgcn_mfma_f64_16x16x4f64(a3, b2, acc[3][2], 0, 0, 0);
      acc[3][3] = __builtin_amdgcn_mfma_f64_16x16x4f64(a3, b3, acc[3][3], 0, 0, 0);
    }
  }

  // ---- probe the true C/D slot->(row,col) mapping ----
  // D1 = A1*B1 with A1[i][k] built from a=lane, B1=ones => D1[i][j] = 4i+96.
  // D2 with A2=ones, b=lane => D2[i][j] = 4j+96. Exact small integers in fp64.
  d4 p1 = (d4){0.0, 0.0, 0.0, 0.0}, p2 = (d4){0.0, 0.0, 0.0, 0.0};
  p1 = __builtin_amdgcn_mfma_f64_16x16x4f64((double)lane, 1.0, p1, 0, 0, 0);
  p2 = __builtin_amdgcn_mfma_f64_16x16x4f64(1.0, (double)lane, p2, 0, 0, 0);
  int rowp[4], colp[4];
#pragma unroll
  for (int r = 0; r < 4; ++r) {
    rowp[r] = ((int)((p1[r] - 96.0) * 0.25)) & 15;
    colp[r] = ((int)((p2[r] - 96.0) * 0.25)) & 15;
  }

  // epilogue: + 0.5 * exp(-sq_dist/10000), exp via 4th-order Taylor (x<=2e-4, err ~1e-20)
  const float* cb = coords + (size_t)(cs + ci) * NPTS * 2;
  float* Sb = S + (size_t)ci * NPTS * NPTS;
#pragma unroll
  for (int r = 0; r < 4; ++r) {
    const int rl = rowp[r], cl = colp[r];
#pragma unroll
    for (int tr = 0; tr < 4; ++tr) {
      const int rowi = i0 + wr + tr * 16 + rl;
      float2 pi = *(const float2*)(cb + 2 * rowi);
      const double cix = pi.x, ciy = pi.y;
#pragma unroll
      for (int tc = 0; tc < 4; ++tc) {
        const int colj = j0 + wc + tc * 16 + cl;
        float2 pj = *(const float2*)(cb + 2 * colj);
        double dx = cix - (double)pj.x, dy = ciy - (double)pj.y;
        double x = (dx * dx + dy * dy) * (1.0 / 10000.0);
        double e = 1.0 - x * (1.0 - x * (0.5 - x * ((1.0 / 6.0) - x * (1.0 / 24.0))));
        Sb[(size_t)rowi * NPTS + colj] = (float)(acc[tr][tc][r] + 0.5 * e);
      }
    }
  }
}

// ---------------- mirror: fill strictly-lower 128-blocks from upper triangle ----------------
__global__ __launch_bounds__(256) void mirror_k(float* __restrict__ S) {
  const int Cb = blockIdx.x, Rb = blockIdx.y;
  if ((Rb >> 1) <= (Cb >> 1)) return;
  float* Sb = S + (size_t)blockIdx.z * NPTS * NPTS;
  __shared__ float t[64][65];
  const int lane = threadIdx.x & 63, w = threadIdx.x >> 6;
#pragma unroll
  for (int p = 0; p < 16; ++p) {
    const int r = w + 4 * p;
    t[r][lane] = Sb[(size_t)(Cb * 64 + r) * NPTS + Rb * 64 + lane];
  }
  __syncthreads();
#pragma unroll
  for (int p = 0; p < 16; ++p) {
    const int r = w + 4 * p;
    Sb[(size_t)(Rb * 64 + r) * NPTS + Cb * 64 + lane] = t[lane][r];
  }
}

// ---------------- monotone fp32 key: a > b (float) <=> mono(a) > mono(b) (uint) ----------------
__device__ __forceinline__ unsigned mono(float f) {
  unsigned u = __float_as_uint(f);
  return (u & 0x80000000u) ? ~u : (u | 0x80000000u);
}

// ---------------- DPP wave-64 reductions (rocPRIM gfx9 pattern), result broadcast ----------------
#define DPP_RED_STEP(OP, X, CTRL, RMASK) \
  X = OP(X, (unsigned)__builtin_amdgcn_update_dpp((int)(X), (int)(X), CTRL, RMASK, 0xf, false))
__device__ __forceinline__ unsigned umaxu(unsigned a, unsigned b) { return a > b ? a : b; }
__device__ __forceinline__ unsigned uminu(unsigned a, unsigned b) { return a < b ? a : b; }

__device__ __forceinline__ unsigned wave_max_bcast(unsigned x) {
  DPP_RED_STEP(umaxu, x, 0x111, 0xf);  // row_shr:1
  DPP_RED_STEP(umaxu, x, 0x112, 0xf);  // row_shr:2
  DPP_RED_STEP(umaxu, x, 0x114, 0xf);  // row_shr:4
  DPP_RED_STEP(umaxu, x, 0x118, 0xf);  // row_shr:8
  DPP_RED_STEP(umaxu, x, 0x142, 0xa);  // row_bcast:15 -> rows 1,3
  DPP_RED_STEP(umaxu, x, 0x143, 0xc);  // row_bcast:31 -> rows 2,3
  return (unsigned)__builtin_amdgcn_readlane((int)x, 63);
}
__device__ __forceinline__ unsigned wave_min_bcast(unsigned x) {
  DPP_RED_STEP(uminu, x, 0x111, 0xf);
  DPP_RED_STEP(uminu, x, 0x112, 0xf);
  DPP_RED_STEP(uminu, x, 0x114, 0xf);
  DPP_RED_STEP(uminu, x, 0x118, 0xf);
  DPP_RED_STEP(uminu, x, 0x142, 0xa);
  DPP_RED_STEP(uminu, x, 0x143, 0xc);
  return (unsigned)__builtin_amdgcn_readlane((int)x, 63);
}

// ---------------- cand_k: per-row lane-top-2 candidates + tau + fp64 rowsum ----------------
__global__ __launch_bounds__(64) void cand_k(const float* __restrict__ S,
                                             float4* __restrict__ cand,
                                             unsigned* __restrict__ montau,
                                             double* __restrict__ rs) {
  const size_t r = blockIdx.x;               // ci*NPTS + row
  const float* row = S + r * NPTS;
  const int lane = threadIdx.x;
  float v0 = -INFINITY, v1 = -INFINITY, v2 = -INFINITY;
  int i0 = 0, i1 = 0;
  double sum = 0.0;
#pragma unroll
  for (int c = 0; c < 8; ++c) {
    float4 q = ((const float4*)row)[c * 64 + lane];
    const int base = c * 256 + 4 * lane;
    float xs[4] = {q.x, q.y, q.z, q.w};
#pragma unroll
    for (int s = 0; s < 4; ++s) {
      float x = xs[s];
      sum += (double)x;
      if (x > v1) {
        if (x > v0) { v2 = v1; v1 = v0; i1 = i0; v0 = x; i0 = base + s; }
        else        { v2 = v1; v1 = x; i1 = base + s; }
      } else if (x > v2) v2 = x;
    }
  }
  cand[r * 64 + lane] = make_float4(v0, __int_as_float(i0), v1, __int_as_float(i1));
  float t = v2;
  for (int off = 32; off > 0; off >>= 1) {
    t = fmaxf(t, __shfl_down(t, off));
    sum += __shfl_down(sum, off);
  }
  if (lane == 0) { montau[r] = mono(t); rs[r] = sum; }
}

// ---------------- greedy traversal: one wave per batch, candidate fast path ----------------
__global__ __launch_bounds__(64) void traverse_k(const float* __restrict__ S,
                                                 const float4* __restrict__ cand,
                                                 const unsigned* __restrict__ montau,
                                                 const double* __restrict__ rs,
                                                 float* __restrict__ order_f, int cs) {
  const int ci = blockIdx.x;
  const int gb = cs + ci;
  const int lane = threadIdx.x;

  const double* rb = rs + (size_t)ci * NPTS;
  double dv = -1.0e300; int di = 0;
#pragma unroll
  for (int c = 0; c < 32; ++c) {
    int j = c * 64 + lane;
    double v = rb[j];
    if (v > dv) { dv = v; di = j; }
  }
  for (int off = 32; off > 0; off >>= 1) {
    double vo = __shfl_down(dv, off);
    int io = __shfl_down(di, off);
    if (vo > dv || (vo == dv && io < di)) { dv = vo; di = io; }
  }
  int cur = __shfl(di, 0);

  unsigned vis = 0, visw = 0;
  if (lane == ((cur >> 2) & 63)) vis |= 1u << (((cur >> 8) << 2) | (cur & 3));
  if (lane == (cur >> 5))        visw |= 1u << (cur & 31);
  if (lane == 0) order_f[(size_t)gb * NPTS] = (float)cur;

  const float*  Sb = S + (size_t)ci * NPTS * NPTS;
  const float4* cb = cand + (size_t)ci * NPTS * 64;
  const unsigned* tb = montau + (size_t)ci * NPTS;

  for (int s = 1; s < NPTS; ++s) {
    const float4 cq = cb[(size_t)cur * 64 + lane];
    const unsigned ktau = tb[cur];
    unsigned k0 = mono(cq.x), k1 = mono(cq.z);
    int i0 = __float_as_int(cq.y), i1 = __float_as_int(cq.w);
    unsigned w0 = (unsigned)__shfl((int)visw, i0 >> 5);
    unsigned w1 = (unsigned)__shfl((int)visw, i1 >> 5);
    unsigned ka = ((w0 >> (i0 & 31)) & 1u) ? 0u : k0;
    unsigned kb = ((w1 >> (i1 & 31)) & 1u) ? 0u : k1;
    unsigned kl, il;
    if (kb > ka) { kl = kb; il = (unsigned)i1; } else { kl = ka; il = (unsigned)i0; }
    const unsigned kmax = wave_max_bcast(kl);
    int nxt;
    if (kmax > ktau) {
      unsigned cidx = (kl == kmax) ? il : 0xFFFFFFFFu;
      nxt = (int)wave_min_bcast(cidx);
    } else {
      const float4* rowp = (const float4*)(Sb + (size_t)cur * NPTS);
      float4 v[8];
#pragma unroll
      for (int c = 0; c < 8; ++c) v[c] = rowp[c * 64 + lane];
      float bv = -INFINITY; int bi = 0;
#pragma unroll
      for (int c = 0; c < 8; ++c) {
        const int base = c * 256 + 4 * lane;
        float x0 = (vis & (1u << (4 * c + 0))) ? -INFINITY : v[c].x;
        float x1 = (vis & (1u << (4 * c + 1))) ? -INFINITY : v[c].y;
        float x2 = (vis & (1u << (4 * c + 2))) ? -INFINITY : v[c].z;
        float x3 = (vis & (1u << (4 * c + 3))) ? -INFINITY : v[c].w;
        if (x0 > bv) { bv = x0; bi = base + 0; }
        if (x1 > bv) { bv = x1; bi = base + 1; }
        if (x2 > bv) { bv = x2; bi = base + 2; }
        if (x3 > bv) { bv = x3; bi = base + 3; }
      }
      unsigned klf = mono(bv);
      const unsigned kmaxf = wave_max_bcast(klf);
      unsigned cidx = (klf == kmaxf) ? (unsigned)bi : 0xFFFFFFFFu;
      nxt = (int)wave_min_bcast(cidx);
    }
    if (lane == ((nxt >> 2) & 63)) vis |= 1u << (((nxt >> 8) << 2) | (nxt & 3));
    if (lane == (nxt >> 5))        visw |= 1u << (nxt & 31);
    if (lane == 0) order_f[(size_t)gb * NPTS + s] = (float)nxt;
    cur = nxt;
  }
}

// ---------------- gather: reordered = features[order] ----------------
__global__ void gather_k(const float* __restrict__ feat, const float* __restrict__ order_f,
                         float* __restrict__ out) {
  const int bk = blockIdx.x;
  const int b = bk >> 11, k = bk & (NPTS - 1);
  const int idx = (int)order_f[(size_t)b * NPTS + k];
  const float4* src = (const float4*)(feat + ((size_t)b * NPTS + idx) * DIM);
  float4* dst = (float4*)(out + ((size_t)b * NPTS + k) * DIM);
  dst[threadIdx.x] = src[threadIdx.x];
}

extern "C" void kernel_launch(void* const* d_in, const int* in_sizes, int n_in,
                              void* d_out, int out_size, void* d_ws, size_t ws_size,
                              hipStream_t stream) {
  const float* features = (const float*)d_in[0];
  const float* coords   = (const float*)d_in[1];
  float* out = (float*)d_out;
  float* order_f = out + (size_t)BATCH * NPTS * DIM;

  // ws per batch: rs (N*8) + montau (N*4) + S (N*N*4) + fn (N*D*4) + cand (N*64*16)
  const size_t per_b = (size_t)NPTS * 8 + (size_t)NPTS * 4 + (size_t)NPTS * NPTS * 4 +
                       (size_t)NPTS * DIM * 4 + (size_t)NPTS * 64 * 16;
  int C = BATCH;
  while (C > 1 && per_b * (size_t)C > ws_size) C >>= 1;

  char* wp = (char*)d_ws;
  double*   rowsum = (double*)wp;                 wp += (size_t)C * NPTS * 8;
  unsigned* mtau   = (unsigned*)wp;               wp += (size_t)C * NPTS * 4;
  float*    S      = (float*)wp;                  wp += (size_t)C * NPTS * NPTS * 4;
  float*    fn     = (float*)wp;                  wp += (size_t)C * NPTS * DIM * 4;
  float4*   cand   = (float4*)wp;

  for (int cs = 0; cs < BATCH; cs += C) {
    normalize_k<<<dim3(C * NPTS), dim3(256), 0, stream>>>(features, fn, cs);
    gemm_k<<<dim3(16, 16, C), dim3(256), 0, stream>>>(fn, coords, S, cs);
    mirror_k<<<dim3(32, 32, C), dim3(256), 0, stream>>>(S);
    cand_k<<<dim3(C * NPTS), dim3(64), 0, stream>>>(S, cand, mtau, rowsum);
    traverse_k<<<dim3(C), dim3(64), 0, stream>>>(S, cand, mtau, rowsum, order_f, cs);
  }
  gather_k<<<dim3(BATCH * NPTS), dim3(192), 0, stream>>>(features, order_f, out);
}